// Round 4
// baseline (329.362 us; speedup 1.0000x reference)
//
#include <hip/hip_runtime.h>

#define KS     11
#define HH     512
#define WW     512
#define OUTD   502         // HH - KS + 1
#define OH     45          // output rows emitted per band
#define ROWS   55          // OH + KS - 1 = 5*11 staged rows (multiple of KS, no waste)
#define NBANDS 12          // 12*45 = 540 >= 502
#define NSTRIP 4           // column strips of 128 output cols
#define SCOLS  128         // output cols per strip (64 threads x 2)
#define LCOLS  140         // staged cols per strip: 138 needed, 140 for float2 parity
#define NIMG   96          // N*C = 32*3
#define NACC   256         // max accumulator slots (used only if workspace fits)

// Barrier-free streaming separable SSIM, sum/difference form.
//  s = x+y, d = x-y; only 4 convolved quantities {s, d, s^2, d^2}:
//    4 mu_x mu_y      = ms^2 - md^2      2(mu_x^2+mu_y^2)   = ms^2 + md^2
//    4 conv(xy)       = Sss - Sdd        2(conv x^2 + y^2)  = Sss + Sdd
//  (factors fold into doubled constants; verified absmax 0.0 in R1/R2).
//
//  R2 post-mortem: VALUBusy 61.5% at unchanged dur -> stall-bound on the
//  per-row __syncthreads convoy. Fix: block = 1 wave, wave-private column
//  strip (stages its own 12-col halo), so every LDS dependency is
//  intra-wave and in-order -> ZERO barriers in the kernel.
//  R3 post-mortem: container died; only kernel-side fault candidate was
//  assuming ws_size >= 2KB. Slot count now chosen host-side from ws_size.
__global__ __launch_bounds__(64, 2)
void ssim_main(const float* __restrict__ xg, const float* __restrict__ yg,
               const float* __restrict__ win, double* __restrict__ acc_out,
               const int accmask)
{
    __shared__ float shs[2][LCOLS];   // s = x+y (this wave's strip)
    __shared__ float shd[2][LCOLS];   // d = x-y

    const int tid   = threadIdx.x;            // 0..63
    const int bid   = blockIdx.x;
    const int strip = bid & (NSTRIP - 1);
    const int band  = (bid >> 2) % NBANDS;
    const int img   = bid / (NSTRIP * NBANDS);
    const int row0  = band * OH;
    const int colb  = strip * SCOLS;          // strip's first output col
    const int c0    = colb + 2 * tid;         // this thread's 2 output cols
    const int l0    = 2 * tid;                // LDS index of own cols

    // Recover 1D gaussian from the (normalized, rank-1) 2D window: row sums.
    // Symmetric: store g[0..5], fold index at compile time.
    float g[6];
    #pragma unroll
    for (int i = 0; i < 6; i++) {
        float s = 0.f;
        #pragma unroll
        for (int j = 0; j < KS; j++) s += win[i * KS + j];
        g[i] = s;
    }
#define G(j) g[(j) <= 5 ? (j) : 10 - (j)]

    const float* xi = xg + (size_t)img * (HH * WW);
    const float* yi = yg + (size_t)img * (HH * WW);

    // halo: threads 0..5 also stage cols colb+128 .. colb+139 (clamped to image)
    const bool hn = (tid < (LCOLS - SCOLS) / 2);
    int hcol = colb + SCOLS + 2 * tid;
    if (hcol > WW - 2) hcol = WW - 2;         // strip 3 halo: clamp, stays finite

    // rotating vertical accumulators [quantity][col][slot]; q: 0=s 1=d 2=s2 3=d2
    // slot emitted at row r is overwritten (mul) at row r+1 -> no reset pass.
    float acc[4][2][KS];
    #pragma unroll
    for (int q = 0; q < 4; q++)
        #pragma unroll
        for (int c = 0; c < 2; c++)
            #pragma unroll
            for (int s = 0; s < KS; s++) acc[q][c][s] = 0.f;

    float ssum = 0.f;
    const float C1x2 = 0.0002f;  // 2*(0.01)^2
    const float C2x2 = 0.0018f;  // 2*(0.03)^2

    // ---- prologue: stage row 0 into buf0; prefetch row 1 into regs ----
    float2 pfs, pfd, phs, phd;
    {
        int gr = row0;                         // row0 <= 495 < 512, no clamp
        float2 ax = *(const float2*)&xi[gr * WW + c0];
        float2 ay = *(const float2*)&yi[gr * WW + c0];
        shs[0][l0] = ax.x + ay.x; shs[0][l0 + 1] = ax.y + ay.y;
        shd[0][l0] = ax.x - ay.x; shd[0][l0 + 1] = ax.y - ay.y;
        if (hn) {
            float2 bx = *(const float2*)&xi[gr * WW + hcol];
            float2 by = *(const float2*)&yi[gr * WW + hcol];
            shs[0][SCOLS + l0] = bx.x + by.x; shs[0][SCOLS + l0 + 1] = bx.y + by.y;
            shd[0][SCOLS + l0] = bx.x - by.x; shd[0][SCOLS + l0 + 1] = bx.y - by.y;
        }
        gr = row0 + 1;
        ax = *(const float2*)&xi[gr * WW + c0];
        ay = *(const float2*)&yi[gr * WW + c0];
        pfs = make_float2(ax.x + ay.x, ax.y + ay.y);
        pfd = make_float2(ax.x - ay.x, ax.y - ay.y);
        phs = make_float2(0.f, 0.f); phd = make_float2(0.f, 0.f);
        if (hn) {
            float2 bx = *(const float2*)&xi[gr * WW + hcol];
            float2 by = *(const float2*)&yi[gr * WW + hcol];
            phs = make_float2(bx.x + by.x, bx.y + by.y);
            phd = make_float2(bx.x - by.x, bx.y - by.y);
        }
    }

    #pragma unroll 1
    for (int rb = 0; rb < ROWS / KS; rb++) {
        #pragma unroll
        for (int rr = 0; rr < KS; rr++) {
            const int r = rb * KS + rr;

            // ---- read 12 s / 12 d for row r from wave-private LDS ----
            const float* sb = shs[r & 1];
            const float* db = shd[r & 1];
            float sv[12], dv[12];
            #pragma unroll
            for (int k = 0; k < 6; k++) {
                float2 a = *(const float2*)&sb[l0 + 2 * k];
                float2 b = *(const float2*)&db[l0 + 2 * k];
                sv[2 * k] = a.x; sv[2 * k + 1] = a.y;
                dv[2 * k] = b.x; dv[2 * k + 1] = b.y;
            }

            // ---- stage prefetched row r+1; prefetch row r+2 ----
            // DS ops from one wave are processed in order: iter r+1's write to
            // buf[(r+1)&1] cannot pass this iter's reads of buf[r&1], and the
            // next iter's reads follow this write in program order. No barrier.
            if (r + 1 < ROWS) {
                float* sw = shs[(r + 1) & 1];
                float* dw = shd[(r + 1) & 1];
                sw[l0] = pfs.x; sw[l0 + 1] = pfs.y;
                dw[l0] = pfd.x; dw[l0 + 1] = pfd.y;
                if (hn) {
                    sw[SCOLS + l0] = phs.x; sw[SCOLS + l0 + 1] = phs.y;
                    dw[SCOLS + l0] = phd.x; dw[SCOLS + l0 + 1] = phd.y;
                }
            }
            if (r + 2 < ROWS) {
                int gr = row0 + r + 2; if (gr > HH - 1) gr = HH - 1;
                float2 ax = *(const float2*)&xi[gr * WW + c0];
                float2 ay = *(const float2*)&yi[gr * WW + c0];
                pfs = make_float2(ax.x + ay.x, ax.y + ay.y);
                pfd = make_float2(ax.x - ay.x, ax.y - ay.y);
                if (hn) {
                    float2 bx = *(const float2*)&xi[gr * WW + hcol];
                    float2 by = *(const float2*)&yi[gr * WW + hcol];
                    phs = make_float2(bx.x + by.x, bx.y + by.y);
                    phd = make_float2(bx.x - by.x, bx.y - by.y);
                }
            }

            // ---- horizontal 11-tap conv, 2 cols x 4 quantities ----
            float h0a = 0.f, h0b = 0.f, h1a = 0.f, h1b = 0.f;
            float h2a = 0.f, h2b = 0.f, h3a = 0.f, h3b = 0.f;
            float ts = sv[0] * sv[0];
            float td = dv[0] * dv[0];
            #pragma unroll
            for (int j = 0; j < KS; j++) {
                const float gj  = G(j);
                const float tsn = sv[j + 1] * sv[j + 1];
                const float tdn = dv[j + 1] * dv[j + 1];
                h0a = fmaf(gj, sv[j],     h0a); h0b = fmaf(gj, sv[j + 1], h0b);
                h1a = fmaf(gj, dv[j],     h1a); h1b = fmaf(gj, dv[j + 1], h1b);
                h2a = fmaf(gj, ts,        h2a); h2b = fmaf(gj, tsn,       h2b);
                h3a = fmaf(gj, td,        h3a); h3b = fmaf(gj, tdn,       h3b);
                ts = tsn; td = tdn;
            }

            // ---- vertical accumulate into rotating slots ----
            // i == 0 targets slot rr (emitted last row): OVERWRITE (mul).
            {
                const float g0 = G(0);
                acc[0][0][rr] = g0 * h0a; acc[0][1][rr] = g0 * h0b;
                acc[1][0][rr] = g0 * h1a; acc[1][1][rr] = g0 * h1b;
                acc[2][0][rr] = g0 * h2a; acc[2][1][rr] = g0 * h2b;
                acc[3][0][rr] = g0 * h3a; acc[3][1][rr] = g0 * h3b;
            }
            #pragma unroll
            for (int i = 1; i < KS; i++) {
                const int slot = (rr - i + KS) % KS;
                const float gi = G(i);
                acc[0][0][slot] = fmaf(gi, h0a, acc[0][0][slot]);
                acc[0][1][slot] = fmaf(gi, h0b, acc[0][1][slot]);
                acc[1][0][slot] = fmaf(gi, h1a, acc[1][0][slot]);
                acc[1][1][slot] = fmaf(gi, h1b, acc[1][1][slot]);
                acc[2][0][slot] = fmaf(gi, h2a, acc[2][0][slot]);
                acc[2][1][slot] = fmaf(gi, h2b, acc[2][1][slot]);
                acc[3][0][slot] = fmaf(gi, h3a, acc[3][0][slot]);
                acc[3][1][slot] = fmaf(gi, h3b, acc[3][1][slot]);
            }

            // ---- emit completed output row jloc = r-10 (slot (rr+1)%11) ----
            const int es   = (rr + 1) % KS;
            const int jloc = r - (KS - 1);
            if (jloc >= 0 && jloc < OH && (row0 + jloc) < OUTD) {
                #pragma unroll
                for (int c = 0; c < 2; c++) {
                    if (c0 + c < OUTD) {
                        const float ms = acc[0][c][es], md = acc[1][c][es];
                        const float Ss = acc[2][c][es], Sd = acc[3][c][es];
                        const float a = ms * ms, b = md * md;
                        const float P = a - b;        // 4 mu_x mu_y
                        const float Q = a + b;        // 2(mu_x^2 + mu_y^2)
                        const float U = Ss - Sd;      // 4 conv(xy)
                        const float V = Ss + Sd;      // 2(conv x^2 + conv y^2)
                        const float num = (P + C1x2) * ((U - P) + C2x2);
                        const float den = (Q + C1x2) * ((V - Q) + C2x2);
                        float rc = __builtin_amdgcn_rcpf(den);
                        rc = rc * fmaf(-den, rc, 2.0f);   // one NR step
                        ssum = fmaf(num, rc, ssum);
                    }
                }
            }
        }
    }

    // single-wave block: shuffle reduce, one atomic into a spread slot
    #pragma unroll
    for (int off = 32; off > 0; off >>= 1)
        ssum += __shfl_down(ssum, off);
    if (tid == 0)
        atomicAdd(&acc_out[bid & accmask], (double)ssum);
}

__global__ void ssim_finalize(const double* __restrict__ acc, float* __restrict__ out,
                              const int nacc)
{
    double s = 0.0;
    for (int i = threadIdx.x; i < nacc; i += 64) s += acc[i];
    #pragma unroll
    for (int off = 32; off > 0; off >>= 1)
        s += __shfl_down(s, off);
    if (threadIdx.x == 0)
        out[0] = (float)(s * (1.0 / 24192384.0));   // 96*502*502 outputs
}

extern "C" void kernel_launch(void* const* d_in, const int* in_sizes, int n_in,
                              void* d_out, int out_size, void* d_ws, size_t ws_size,
                              hipStream_t stream)
{
    const float* x   = (const float*)d_in[0];
    const float* y   = (const float*)d_in[1];
    const float* win = (const float*)d_in[2];
    float* out = (float*)d_out;
    double* acc = (double*)d_ws;

    // R3 lesson: never assume workspace size. Use spread slots only if they fit.
    const int nacc = (ws_size >= NACC * sizeof(double)) ? NACC : 1;
    hipMemsetAsync(acc, 0, nacc * sizeof(double), stream);
    ssim_main<<<dim3(NIMG * NBANDS * NSTRIP), dim3(64), 0, stream>>>(
        x, y, win, acc, nacc - 1);
    ssim_finalize<<<dim3(1), dim3(64), 0, stream>>>(acc, out, nacc);
}

// Round 5
// 274.086 us; speedup vs baseline: 1.2017x; 1.2017x over previous
//
#include <hip/hip_runtime.h>

#define KS     11
#define HH     512
#define WW     512
#define OUTD   502         // HH - KS + 1
#define OH     133         // output rows per band
#define ROWS   143         // OH + KS - 1 = 13*11 (multiple of KS)
#define NBANDS 4           // 4*133 = 532 >= 502
#define ECOLS  52          // emitted cols per wave (64 staged - 12 halo)
#define NSTRIP 10          // 10*52 = 520 >= 502
#define NIMG   96          // N*C = 32*3
#define NACC   256         // max accumulator slots (used only if workspace fits)

// Pair-split shuffle SSIM (no LDS, no barriers), sum/difference form:
//   s = x+y, d = x-y; 4 convolved quantities {s, d, s^2, d^2}:
//     4 mu_x mu_y = ms^2-md^2   2(mu_x^2+mu_y^2) = ms^2+md^2
//     4 conv(xy)  = Sss-Sdd     2(conv x^2+y^2)  = Sss+Sdd
//   (factors fold into doubled constants; absmax 0.0 verified R1/R2/R4).
//
// R4 post-mortem: barrier removal made it SLOWER; VALU issue ~2.3x the
// algorithmic floor across R0/R2/R4 -> per-thread acc state (88 floats,
// all touched every row) lives in AGPRs; each row pays accvgpr round
// trips + LDS unpack movs. Fix: lane PAIR owns a col pair; even lane
// convolves {s, s^2}, odd {d, d^2} -> 44-float acc state fits VGPRs.
// Halo via __shfl_down (DS pipe, conflict-free); quantities reunited at
// emit via shfl_xor (all gates pair-uniform so shuffles are safe).
__global__ __launch_bounds__(64, 4)
void ssim_main(const float* __restrict__ xg, const float* __restrict__ yg,
               const float* __restrict__ win, double* __restrict__ acc_out,
               const int accmask)
{
    const int lane   = threadIdx.x;           // 0..63
    const int bid    = blockIdx.x;
    const int strip  = bid % NSTRIP;
    const int band   = (bid / NSTRIP) % NBANDS;
    const int img    = bid / (NSTRIP * NBANDS);
    const int row0   = band * OH;
    const int parity = lane & 1;

    // Recover 1D gaussian from the (normalized, rank-1) 2D window: row sums.
    // Symmetric: store g[0..5], fold index at compile time.
    float g[6];
    #pragma unroll
    for (int i = 0; i < 6; i++) {
        float s = 0.f;
        #pragma unroll
        for (int j = 0; j < KS; j++) s += win[i * KS + j];
        g[i] = s;
    }
#define G(j) g[(j) <= 5 ? (j) : 10 - (j)]

    // Pair p = lane>>1 owns staged cols (2p, 2p+1) of this strip.
    // Even lane loads x there, odd lane loads y there (same cols).
    int gcol = ECOLS * strip + (lane & ~1);
    if (gcol > WW - 2) gcol = WW - 2;         // strip 9 tail: clamp, finite garbage, gated
    const float* srcp = (parity ? yg : xg) + (size_t)img * (HH * WW) + gcol;
    const float sgn = parity ? -1.f : 1.f;    // v = fmaf(sgn, own, partner): s or d

    // rotating vertical accumulators [q: 0=v, 1=v^2][col][slot] -- 44 floats.
    // Slot emitted at row r is overwritten (mul) at row r+1 -> no reset pass.
    float acc[2][2][KS];
    #pragma unroll
    for (int q = 0; q < 2; q++)
        #pragma unroll
        for (int c = 0; c < 2; c++)
            #pragma unroll
            for (int s = 0; s < KS; s++) acc[q][c][s] = 0.f;

    float ssum = 0.f;
    const float C1x2 = 0.0002f;  // 2*(0.01)^2
    const float C2x2 = 0.0018f;  // 2*(0.03)^2

    // prefetch row0 (depth-1; 16 waves/CU TLP hides the rest)
    float2 pf = *(const float2*)(srcp + (size_t)row0 * WW);

    #pragma unroll 1
    for (int rb = 0; rb < ROWS / KS; rb++) {
        #pragma unroll
        for (int rr = 0; rr < KS; rr++) {
            const int r = rb * KS + rr;

            // consume prefetched row r; issue load for row r+1 immediately
            const float2 cur = pf;
            {
                int gr = row0 + r + 1; if (gr > HH - 1) gr = HH - 1;
                pf = *(const float2*)(srcp + (size_t)gr * WW);
            }

            // partner exchange: even gets y, odd gets x -> v = s (even) / d (odd)
            const float px = __shfl_xor(cur.x, 1);
            const float py = __shfl_xor(cur.y, 1);
            const float v0 = fmaf(sgn, cur.x, px);
            const float v1 = fmaf(sgn, cur.y, py);

            // halo gather: staged cols 2p..2p+11 of own quantity via shfl_down
            float sv[12];
            sv[0] = v0; sv[1] = v1;
            #pragma unroll
            for (int k = 1; k <= 5; k++) {
                sv[2 * k]     = __shfl_down(v0, 2 * k);
                sv[2 * k + 1] = __shfl_down(v1, 2 * k);
            }

            // horizontal 11-tap conv of {v, v^2} for 2 cols (rolling square)
            float hv0 = 0.f, hv1 = 0.f, hq0 = 0.f, hq1 = 0.f;
            float q0 = sv[0] * sv[0];
            #pragma unroll
            for (int j = 0; j < KS; j++) {
                const float gj = G(j);
                const float q1 = sv[j + 1] * sv[j + 1];
                hv0 = fmaf(gj, sv[j],     hv0);
                hv1 = fmaf(gj, sv[j + 1], hv1);
                hq0 = fmaf(gj, q0,        hq0);
                hq1 = fmaf(gj, q1,        hq1);
                q0 = q1;
            }

            // vertical accumulate; i==0 targets slot rr (emitted last row): overwrite
            {
                const float g0 = G(0);
                acc[0][0][rr] = g0 * hv0; acc[0][1][rr] = g0 * hv1;
                acc[1][0][rr] = g0 * hq0; acc[1][1][rr] = g0 * hq1;
            }
            #pragma unroll
            for (int i = 1; i < KS; i++) {
                const int slot = (rr - i + KS) % KS;
                const float gi = G(i);
                acc[0][0][slot] = fmaf(gi, hv0, acc[0][0][slot]);
                acc[0][1][slot] = fmaf(gi, hv1, acc[0][1][slot]);
                acc[1][0][slot] = fmaf(gi, hq0, acc[1][0][slot]);
                acc[1][1][slot] = fmaf(gi, hq1, acc[1][1][slot]);
            }

            // emit completed output row jloc = r-10 (slot (rr+1)%11).
            // Lane emits ONE col: ecol = strip base + lane. All gates are
            // pair-uniform (ECOLS and OUTD even), so the shfl_xor pairs below
            // always have both partners active.
            const int es   = (rr + 1) % KS;
            const int jloc = r - (KS - 1);
            const int ecol = ECOLS * strip + lane;
            if (jloc >= 0 && jloc < OH && (row0 + jloc) < OUTD &&
                lane < ECOLS && ecol < OUTD) {
                // reunite quantities: even lane has (ms,Ss) pair, odd has (md,Sd)
                const float pm0 = __shfl_xor(acc[0][0][es], 1);
                const float pm1 = __shfl_xor(acc[0][1][es], 1);
                const float pS0 = __shfl_xor(acc[1][0][es], 1);
                const float pS1 = __shfl_xor(acc[1][1][es], 1);
                const float ms = parity ? pm1 : acc[0][0][es];
                const float md = parity ? acc[0][1][es] : pm0;
                const float Ss = parity ? pS1 : acc[1][0][es];
                const float Sd = parity ? acc[1][1][es] : pS0;
                const float a = ms * ms, b = md * md;
                const float P = a - b;        // 4 mu_x mu_y
                const float Q = a + b;        // 2(mu_x^2 + mu_y^2)
                const float U = Ss - Sd;      // 4 conv(xy)
                const float V = Ss + Sd;      // 2(conv x^2 + conv y^2)
                const float num = (P + C1x2) * ((U - P) + C2x2);
                const float den = (Q + C1x2) * ((V - Q) + C2x2);
                float rc = __builtin_amdgcn_rcpf(den);
                rc = rc * fmaf(-den, rc, 2.0f);   // one NR step: ~0.5 ulp
                ssum = fmaf(num, rc, ssum);
            }
        }
    }

    // single-wave block: shuffle reduce, one atomic into a spread slot
    #pragma unroll
    for (int off = 32; off > 0; off >>= 1)
        ssum += __shfl_down(ssum, off);
    if (lane == 0)
        atomicAdd(&acc_out[bid & accmask], (double)ssum);
}

__global__ void ssim_finalize(const double* __restrict__ acc, float* __restrict__ out,
                              const int nacc)
{
    double s = 0.0;
    for (int i = threadIdx.x; i < nacc; i += 64) s += acc[i];
    #pragma unroll
    for (int off = 32; off > 0; off >>= 1)
        s += __shfl_down(s, off);
    if (threadIdx.x == 0)
        out[0] = (float)(s * (1.0 / 24192384.0));   // 96*502*502 outputs
}

extern "C" void kernel_launch(void* const* d_in, const int* in_sizes, int n_in,
                              void* d_out, int out_size, void* d_ws, size_t ws_size,
                              hipStream_t stream)
{
    const float* x   = (const float*)d_in[0];
    const float* y   = (const float*)d_in[1];
    const float* win = (const float*)d_in[2];
    float* out = (float*)d_out;
    double* acc = (double*)d_ws;

    // Never assume workspace size (R3 lesson): spread slots only if they fit.
    const int nacc = (ws_size >= NACC * sizeof(double)) ? NACC : 1;
    hipMemsetAsync(acc, 0, nacc * sizeof(double), stream);
    ssim_main<<<dim3(NIMG * NBANDS * NSTRIP), dim3(64), 0, stream>>>(
        x, y, win, acc, nacc - 1);
    ssim_finalize<<<dim3(1), dim3(64), 0, stream>>>(acc, out, nacc);
}